// Round 20
// baseline (67.023 us; speedup 1.0000x reference)
//
#include <hip/hip_runtime.h>
#include <hip/hip_bf16.h>

#define BB 2
#define SS 1024
#define DD 256
#define NCH 4           // k-chunks in attn
#define KCH 256         // k-chunk size

typedef __attribute__((ext_vector_type(8))) short bf16x8;
typedef __attribute__((ext_vector_type(4))) float f32x4;

__device__ __forceinline__ unsigned short f2bf(float f) {
    __hip_bfloat16 h = __float2bfloat16(f);
    return *reinterpret_cast<unsigned short*>(&h);
}
__device__ __forceinline__ float bf2f(unsigned short u) {
    __hip_bfloat16 h;
    *reinterpret_cast<unsigned short*>(&h) = u;
    return __bfloat162float(h);
}
__device__ __forceinline__ bf16x8 cvt8(float4 f0, float4 f1) {
    bf16x8 o;
    o[0] = (short)f2bf(f0.x); o[1] = (short)f2bf(f0.y);
    o[2] = (short)f2bf(f0.z); o[3] = (short)f2bf(f0.w);
    o[4] = (short)f2bf(f1.x); o[5] = (short)f2bf(f1.y);
    o[6] = (short)f2bf(f1.z); o[7] = (short)f2bf(f1.w);
    return o;
}

// ---------------------------------------------------------------------------
// Kernel 0: fp32->bf16 conversion of the four weight matrices (R19 verbatim).
// ---------------------------------------------------------------------------
__global__ __launch_bounds__(256) void cvt_w(
    const float* __restrict__ Wq, const float* __restrict__ Wk,
    const float* __restrict__ Wv, const float* __restrict__ Wo,
    unsigned short* __restrict__ Wqb, unsigned short* __restrict__ Wkb,
    unsigned short* __restrict__ Wvb, unsigned short* __restrict__ Wob)
{
    const int u = blockIdx.x * 256 + threadIdx.x;   // unit = 8 elements
    const float* src;
    unsigned short* dst;
    int base;
    if (u < 8192)       { src = Wq; dst = Wqb; base = u; }
    else if (u < 16384) { src = Wk; dst = Wkb; base = u - 8192; }
    else if (u < 24576) { src = Wv; dst = Wvb; base = u - 16384; }
    else                { src = Wo; dst = Wob; base = u - 24576; }
    const float4* s4 = (const float4*)src + (size_t)base * 2;
    *(bf16x8*)(dst + (size_t)base * 8) = cvt8(s4[0], s4[1]);
}

// ---------------------------------------------------------------------------
// Kernel 1: Q,K,V projection via MFMA, column-split x2 (R19 verbatim).
// Launched TWICE this round for time attribution (idempotent).
// ---------------------------------------------------------------------------
__global__ __launch_bounds__(256, 2) void qkv_mfma(
    const float* __restrict__ x,
    const unsigned short* __restrict__ Wqb, const float* __restrict__ bq,
    const unsigned short* __restrict__ Wkb, const float* __restrict__ bk,
    const unsigned short* __restrict__ Wvb, const float* __restrict__ bv,
    unsigned short* __restrict__ Qb, unsigned short* __restrict__ Kb,
    unsigned short* __restrict__ VB,
    float* __restrict__ qq, float* __restrict__ kk)   // [2][BB*SS] partials
{
    __shared__ float red[4][16];
    const int t = threadIdx.x;
    const int w = t >> 6, l = t & 63, lr = l & 15, lc = l >> 4;
    const int bx = blockIdx.x;
    const int mat = bx % 3;
    const int rest = bx / 3;
    const int tile = rest >> 1;
    const int ch = rest & 1;                 // column half
    const int r0 = tile * 16;
    const int b = r0 >> 10;
    const int s_in_base = r0 & (SS - 1);
    const size_t rows = (size_t)BB * SS;

    const unsigned short* W = (mat == 0) ? Wqb : (mat == 1) ? Wkb : Wvb;
    const float* bias       = (mat == 0) ? bq  : (mat == 1) ? bk  : bv;

    // A-frags: in-register cvt from fp32 x
    bf16x8 af[8];
#pragma unroll
    for (int db = 0; db < 8; ++db) {
        const float* xp = x + (size_t)(r0 + lr) * DD + db * 32 + 8 * lc;
        af[db] = cvt8(*(const float4*)(xp), *(const float4*)(xp + 4));
    }

    float nrm[4] = {0.f, 0.f, 0.f, 0.f};

#pragma unroll
    for (int cb = 0; cb < 2; ++cb) {
        const int jb = 128 * ch + 32 * w + 16 * cb;
        f32x4 acc = {0.f, 0.f, 0.f, 0.f};
#pragma unroll
        for (int db = 0; db < 8; ++db) {
            bf16x8 bf = *(const bf16x8*)(W + (size_t)(jb + lr) * DD + db * 32 + 8 * lc);
            acc = __builtin_amdgcn_mfma_f32_16x16x32_bf16(af[db], bf, acc, 0, 0, 0);
        }
        const float bv_ = bias[jb + lr];
#pragma unroll
        for (int r = 0; r < 4; ++r) {
            const int srow = r0 + lc * 4 + r;     // C/D: row=(l>>4)*4+r, col=l%16
            const float v = acc[r] + bv_;
            const unsigned short h = f2bf(v);
            if (mat == 0) {
                Qb[(size_t)srow * DD + jb + lr] = h;
                const float hv = bf2f(h); nrm[r] += hv * hv;
            } else if (mat == 1) {
                Kb[(size_t)srow * DD + jb + lr] = h;
                const float hv = bf2f(h); nrm[r] += hv * hv;
            } else {
                // VB layout: tile(b, kb32=s/32, db16=d/16) of 1024B
                const int s_in = s_in_base + lc * 4 + r;
                const int kb32 = s_in >> 5;
                const int kslot = (s_in >> 3) & 3;
                const int jj = s_in & 7;
                const int db16 = ch * 8 + 2 * w + cb;
                const size_t off = ((size_t)((b * 32 + kb32) * 16 + db16) << 9)
                                 + ((kslot * 16 + lr) << 3) + jj;
                VB[off] = h;
            }
        }
    }

    if (mat < 2) {
#pragma unroll
        for (int r = 0; r < 4; ++r) {
            float n = nrm[r];
#pragma unroll
            for (int m = 1; m < 16; m <<= 1) n += __shfl_xor(n, m, 64);
            if (lr == 0) red[w][lc * 4 + r] = n;
        }
        __syncthreads();
        if (t < 16) {
            const float s = red[0][t] + red[1][t] + red[2][t] + red[3][t];
            if (mat == 0) qq[(size_t)ch * rows + r0 + t] = s;
            else          kk[(size_t)ch * rows + r0 + t] = s;
        }
    }
}

// ---------------------------------------------------------------------------
// Kernel 2: partial attention via MFMA (R19 verbatim, single launch).
// ---------------------------------------------------------------------------
__global__ __launch_bounds__(256, 2) void attn_part_mfma(
    const unsigned short* __restrict__ Qb, const unsigned short* __restrict__ Kb,
    const unsigned short* __restrict__ VB,
    const float* __restrict__ qq, const float* __restrict__ kk,  // [2][rows]
    float* __restrict__ Opart, float* __restrict__ esum)
{
    __shared__ unsigned short P_s[16 * 256];   // 8 KB, XOR-swizzled
    __shared__ float kk_s[KCH];
    __shared__ float qq_s[16];
    __shared__ float es_red[4][16];

    const int t = threadIdx.x;
    const int w = t >> 6, l = t & 63, lr = l & 15, lc = l >> 4;
    const int qtile = blockIdx.x >> 2;
    const int c = blockIdx.x & 3;
    const int rowbase = qtile * 16;            // global row
    const int b = rowbase >> 10;
    const int s0 = c * KCH;                    // chunk start within batch
    const size_t rows = (size_t)BB * SS;

    kk_s[t] = kk[b * SS + s0 + t] + kk[rows + b * SS + s0 + t];
    if (t < 16) qq_s[t] = qq[rowbase + t] + qq[rows + rowbase + t];

    // Q A-frags: lane(row=l%16, 8 contiguous d), held in regs for the block
    bf16x8 qf[8];
#pragma unroll
    for (int db = 0; db < 8; ++db)
        qf[db] = *(const bf16x8*)(Qb + (size_t)(rowbase + lr) * DD + db * 32 + 8 * lc);

    __syncthreads();

    // ---- QK^T + exp ----
    float psum[4] = {0.f, 0.f, 0.f, 0.f};
#pragma unroll
    for (int kbi = 0; kbi < 4; ++kbi) {
        const int kb = 64 * w + 16 * kbi;
        f32x4 acc = {0.f, 0.f, 0.f, 0.f};
#pragma unroll
        for (int db = 0; db < 8; ++db) {
            bf16x8 kf = *(const bf16x8*)(
                Kb + (size_t)(b * SS + s0 + kb + lr) * DD + db * 32 + 8 * lc);
            acc = __builtin_amdgcn_mfma_f32_16x16x32_bf16(qf[db], kf, acc, 0, 0, 0);
        }
        const int kcol = kb + lr;
        const float kkv = kk_s[kcol];
#pragma unroll
        for (int r = 0; r < 4; ++r) {
            const int qi = lc * 4 + r;
            const float d2 = fmaxf(qq_s[qi] + kkv - 2.f * acc[r], 0.f);
            const float e = __expf(-sqrtf(d2) * 0.0625f);
            psum[r] += e;
            P_s[qi * 256 + (kcol ^ ((qi & 7) << 3))] = f2bf(e);
        }
    }
    // per-row e-sums: reduce across l%16, then across waves via LDS
#pragma unroll
    for (int r = 0; r < 4; ++r) {
        float s = psum[r];
#pragma unroll
        for (int m = 1; m < 16; m <<= 1) s += __shfl_xor(s, m, 64);
        if (lr == 0) es_red[w][lc * 4 + r] = s;
    }
    __syncthreads();
    if (t < 16)
        esum[(size_t)c * rows + rowbase + t] =
            es_red[0][t] + es_red[1][t] + es_red[2][t] + es_red[3][t];

    // ---- PV ----
    f32x4 acc2[4];
#pragma unroll
    for (int i = 0; i < 4; ++i) acc2[i] = (f32x4){0.f, 0.f, 0.f, 0.f};

#pragma unroll
    for (int ki = 0; ki < 8; ++ki) {
        bf16x8 pf = *(const bf16x8*)(
            P_s + lr * 256 + ((32 * ki + 8 * lc) ^ ((lr & 7) << 3)));
        const size_t tbase =
            ((size_t)((b * 32 + c * 8 + ki) * 16 + 4 * w) << 9) + l * 8;
#pragma unroll
        for (int dbi = 0; dbi < 4; ++dbi) {
            bf16x8 vf = *(const bf16x8*)(VB + tbase + ((size_t)dbi << 9));
            acc2[dbi] = __builtin_amdgcn_mfma_f32_16x16x32_bf16(pf, vf, acc2[dbi], 0, 0, 0);
        }
    }
#pragma unroll
    for (int dbi = 0; dbi < 4; ++dbi)
#pragma unroll
        for (int r = 0; r < 4; ++r)
            Opart[((size_t)c * rows + rowbase + lc * 4 + r) * DD
                  + 64 * w + 16 * dbi + lr] = acc2[dbi][r];
}

// ---------------------------------------------------------------------------
// Kernel 3: chunk-sum + normalize -> bf16 att rows (R19 verbatim).
// Launched TWICE this round for time attribution (idempotent).
// ---------------------------------------------------------------------------
__global__ __launch_bounds__(256) void reduce_att(
    const float* __restrict__ Opart, const float* __restrict__ esum,
    unsigned short* __restrict__ attb)
{
    const size_t rows = (size_t)BB * SS;
    const int u = blockIdx.x * 256 + threadIdx.x;   // 65536 units
    const int row = u >> 5;
    const int d8 = (u & 31) * 8;

    const float inv = 1.f / (esum[row] + esum[rows + row] +
                             esum[2 * rows + row] + esum[3 * rows + row]);

    float s0 = 0.f, s1 = 0.f, s2 = 0.f, s3 = 0.f;
    float s4 = 0.f, s5 = 0.f, s6 = 0.f, s7 = 0.f;
#pragma unroll
    for (int c = 0; c < NCH; ++c) {
        const float* p = Opart + ((size_t)c * rows + row) * DD + d8;
        float4 a0 = *(const float4*)(p);
        float4 a1 = *(const float4*)(p + 4);
        s0 += a0.x; s1 += a0.y; s2 += a0.z; s3 += a0.w;
        s4 += a1.x; s5 += a1.y; s6 += a1.z; s7 += a1.w;
    }
    bf16x8 a;
    a[0] = (short)f2bf(s0 * inv); a[1] = (short)f2bf(s1 * inv);
    a[2] = (short)f2bf(s2 * inv); a[3] = (short)f2bf(s3 * inv);
    a[4] = (short)f2bf(s4 * inv); a[5] = (short)f2bf(s5 * inv);
    a[6] = (short)f2bf(s6 * inv); a[7] = (short)f2bf(s7 * inv);
    *(bf16x8*)(attb + (size_t)row * DD + d8) = a;
}

// ---------------------------------------------------------------------------
// Kernel 4: output projection via MFMA with LDS staging (R19 verbatim).
// Launched TWICE this round for time attribution (idempotent).
// ---------------------------------------------------------------------------
__global__ __launch_bounds__(256, 2) void outproj_mfma(
    const unsigned short* __restrict__ attb,
    const unsigned short* __restrict__ Wob, const float* __restrict__ bo,
    float* __restrict__ out)
{
    __shared__ unsigned short att_s[16 * 264];   // 8.25 KB padded
    const int t = threadIdx.x;
    const int w = t >> 6, l = t & 63, lr = l & 15, lc = l >> 4;
    const int r0 = (blockIdx.x >> 2) * 16;   // global row
    const int ch = blockIdx.x & 3;           // col quarter

#pragma unroll
    for (int i = 0; i < 2; ++i) {
        const int u = t + i * 256;
        const int row = u >> 5;
        const int d8 = (u & 31) * 8;
        *(bf16x8*)(att_s + row * 264 + d8) =
            *(const bf16x8*)(attb + (size_t)(r0 + row) * DD + d8);
    }
    __syncthreads();

    bf16x8 af[8];
#pragma unroll
    for (int db = 0; db < 8; ++db)
        af[db] = *(const bf16x8*)(att_s + lr * 264 + db * 32 + 8 * lc);

    const int jb = 64 * ch + 16 * w;
    f32x4 acc = {0.f, 0.f, 0.f, 0.f};
#pragma unroll
    for (int db = 0; db < 8; ++db) {
        bf16x8 bf = *(const bf16x8*)(Wob + (size_t)(jb + lr) * DD + db * 32 + 8 * lc);
        acc = __builtin_amdgcn_mfma_f32_16x16x32_bf16(af[db], bf, acc, 0, 0, 0);
    }
    const float bov = bo[jb + lr];
#pragma unroll
    for (int r = 0; r < 4; ++r)
        out[(size_t)(r0 + lc * 4 + r) * DD + jb + lr] = acc[r] + bov;
}

// ---------------------------------------------------------------------------
extern "C" void kernel_launch(void* const* d_in, const int* in_sizes, int n_in,
                              void* d_out, int out_size, void* d_ws, size_t ws_size,
                              hipStream_t stream) {
    const float* x  = (const float*)d_in[0];
    const float* Wq = (const float*)d_in[1];
    const float* bq = (const float*)d_in[2];
    const float* Wk = (const float*)d_in[3];
    const float* bk = (const float*)d_in[4];
    const float* Wv = (const float*)d_in[5];
    const float* bv = (const float*)d_in[6];
    const float* Wo = (const float*)d_in[7];
    const float* bo = (const float*)d_in[8];
    float* out = (float*)d_out;

    // ws layout (bf16): Qb | Kb | VB | Wqb | Wkb | Wvb | Wob | attb ||
    //                   qq[2][rows] | kk[2][rows] | esum[4][rows] | Opart (fp32)
    const size_t rows = (size_t)BB * SS;            // 2048
    unsigned short* Qb   = (unsigned short*)d_ws;
    unsigned short* Kb   = Qb + rows * DD;
    unsigned short* VB   = Kb + rows * DD;
    unsigned short* Wqb  = VB + rows * DD;
    unsigned short* Wkb  = Wqb + (size_t)DD * DD;
    unsigned short* Wvb  = Wkb + (size_t)DD * DD;
    unsigned short* Wob  = Wvb + (size_t)DD * DD;
    unsigned short* attb = Wob + (size_t)DD * DD;
    float* qq    = (float*)(attb + rows * DD);       // 2*rows
    float* kk    = qq + 2 * rows;                    // 2*rows
    float* esum  = kk + 2 * rows;                    // NCH*rows
    float* Opart = esum + (size_t)NCH * rows;        // NCH*rows*DD floats

    // ATTRIBUTION: qkv, reduce, outproj doubled (idempotent).
    // dur - 48.55 = t_qkv + t_reduce + t_outproj.
    cvt_w<<<128, 256, 0, stream>>>(Wq, Wk, Wv, Wo, Wqb, Wkb, Wvb, Wob);
    qkv_mfma<<<768, 256, 0, stream>>>(
        x, Wqb, bq, Wkb, bk, Wvb, bv, Qb, Kb, VB, qq, kk);
    qkv_mfma<<<768, 256, 0, stream>>>(
        x, Wqb, bq, Wkb, bk, Wvb, bv, Qb, Kb, VB, qq, kk);
    attn_part_mfma<<<(int)(rows / 16) * NCH, 256, 0, stream>>>(
        Qb, Kb, VB, qq, kk, Opart, esum);
    reduce_att<<<256, 256, 0, stream>>>(Opart, esum, attb);
    reduce_att<<<256, 256, 0, stream>>>(Opart, esum, attb);
    outproj_mfma<<<(int)(rows / 16) * 4, 256, 0, stream>>>(
        attb, Wob, bo, out);
    outproj_mfma<<<(int)(rows / 16) * 4, 256, 0, stream>>>(
        attb, Wob, bo, out);
}

// Round 21
// 47.837 us; speedup vs baseline: 1.4011x; 1.4011x over previous
//
#include <hip/hip_runtime.h>
#include <hip/hip_bf16.h>

#define BB 2
#define SS 1024
#define DD 256
#define NCH 8           // k-chunks in attn
#define KCH 128         // k-chunk size
#define QT 32           // q-rows per attn block

typedef __attribute__((ext_vector_type(8))) short bf16x8;
typedef __attribute__((ext_vector_type(4))) float f32x4;

__device__ __forceinline__ unsigned short f2bf(float f) {
    __hip_bfloat16 h = __float2bfloat16(f);
    return *reinterpret_cast<unsigned short*>(&h);
}
__device__ __forceinline__ float bf2f(unsigned short u) {
    __hip_bfloat16 h;
    *reinterpret_cast<unsigned short*>(&h) = u;
    return __bfloat162float(h);
}
__device__ __forceinline__ bf16x8 cvt8(float4 f0, float4 f1) {
    bf16x8 o;
    o[0] = (short)f2bf(f0.x); o[1] = (short)f2bf(f0.y);
    o[2] = (short)f2bf(f0.z); o[3] = (short)f2bf(f0.w);
    o[4] = (short)f2bf(f1.x); o[5] = (short)f2bf(f1.y);
    o[6] = (short)f2bf(f1.z); o[7] = (short)f2bf(f1.w);
    return o;
}

// ---------------------------------------------------------------------------
// Kernel 0: fp32->bf16 conversion of the four weight matrices (R19 verbatim).
// ---------------------------------------------------------------------------
__global__ __launch_bounds__(256) void cvt_w(
    const float* __restrict__ Wq, const float* __restrict__ Wk,
    const float* __restrict__ Wv, const float* __restrict__ Wo,
    unsigned short* __restrict__ Wqb, unsigned short* __restrict__ Wkb,
    unsigned short* __restrict__ Wvb, unsigned short* __restrict__ Wob)
{
    const int u = blockIdx.x * 256 + threadIdx.x;   // unit = 8 elements
    const float* src;
    unsigned short* dst;
    int base;
    if (u < 8192)       { src = Wq; dst = Wqb; base = u; }
    else if (u < 16384) { src = Wk; dst = Wkb; base = u - 8192; }
    else if (u < 24576) { src = Wv; dst = Wvb; base = u - 16384; }
    else                { src = Wo; dst = Wob; base = u - 24576; }
    const float4* s4 = (const float4*)src + (size_t)base * 2;
    *(bf16x8*)(dst + (size_t)base * 8) = cvt8(s4[0], s4[1]);
}

// ---------------------------------------------------------------------------
// Kernel 1: Q,K,V projection via MFMA, column-split x2 (R19 verbatim).
// ---------------------------------------------------------------------------
__global__ __launch_bounds__(256, 2) void qkv_mfma(
    const float* __restrict__ x,
    const unsigned short* __restrict__ Wqb, const float* __restrict__ bq,
    const unsigned short* __restrict__ Wkb, const float* __restrict__ bk,
    const unsigned short* __restrict__ Wvb, const float* __restrict__ bv,
    unsigned short* __restrict__ Qb, unsigned short* __restrict__ Kb,
    unsigned short* __restrict__ VB,
    float* __restrict__ qq, float* __restrict__ kk)   // [2][BB*SS] partials
{
    __shared__ float red[4][16];
    const int t = threadIdx.x;
    const int w = t >> 6, l = t & 63, lr = l & 15, lc = l >> 4;
    const int bx = blockIdx.x;
    const int mat = bx % 3;
    const int rest = bx / 3;
    const int tile = rest >> 1;
    const int ch = rest & 1;                 // column half
    const int r0 = tile * 16;
    const int b = r0 >> 10;
    const int s_in_base = r0 & (SS - 1);
    const size_t rows = (size_t)BB * SS;

    const unsigned short* W = (mat == 0) ? Wqb : (mat == 1) ? Wkb : Wvb;
    const float* bias       = (mat == 0) ? bq  : (mat == 1) ? bk  : bv;

    // A-frags: in-register cvt from fp32 x
    bf16x8 af[8];
#pragma unroll
    for (int db = 0; db < 8; ++db) {
        const float* xp = x + (size_t)(r0 + lr) * DD + db * 32 + 8 * lc;
        af[db] = cvt8(*(const float4*)(xp), *(const float4*)(xp + 4));
    }

    float nrm[4] = {0.f, 0.f, 0.f, 0.f};

#pragma unroll
    for (int cb = 0; cb < 2; ++cb) {
        const int jb = 128 * ch + 32 * w + 16 * cb;
        f32x4 acc = {0.f, 0.f, 0.f, 0.f};
#pragma unroll
        for (int db = 0; db < 8; ++db) {
            bf16x8 bf = *(const bf16x8*)(W + (size_t)(jb + lr) * DD + db * 32 + 8 * lc);
            acc = __builtin_amdgcn_mfma_f32_16x16x32_bf16(af[db], bf, acc, 0, 0, 0);
        }
        const float bv_ = bias[jb + lr];
#pragma unroll
        for (int r = 0; r < 4; ++r) {
            const int srow = r0 + lc * 4 + r;     // C/D: row=(l>>4)*4+r, col=l%16
            const float v = acc[r] + bv_;
            const unsigned short h = f2bf(v);
            if (mat == 0) {
                Qb[(size_t)srow * DD + jb + lr] = h;
                const float hv = bf2f(h); nrm[r] += hv * hv;
            } else if (mat == 1) {
                Kb[(size_t)srow * DD + jb + lr] = h;
                const float hv = bf2f(h); nrm[r] += hv * hv;
            } else {
                // VB layout: tile(b, kb32=s/32, db16=d/16) of 1024B
                const int s_in = s_in_base + lc * 4 + r;
                const int kb32 = s_in >> 5;
                const int kslot = (s_in >> 3) & 3;
                const int jj = s_in & 7;
                const int db16 = ch * 8 + 2 * w + cb;
                const size_t off = ((size_t)((b * 32 + kb32) * 16 + db16) << 9)
                                 + ((kslot * 16 + lr) << 3) + jj;
                VB[off] = h;
            }
        }
    }

    if (mat < 2) {
#pragma unroll
        for (int r = 0; r < 4; ++r) {
            float n = nrm[r];
#pragma unroll
            for (int m = 1; m < 16; m <<= 1) n += __shfl_xor(n, m, 64);
            if (lr == 0) red[w][lc * 4 + r] = n;
        }
        __syncthreads();
        if (t < 16) {
            const float s = red[0][t] + red[1][t] + red[2][t] + red[3][t];
            if (mat == 0) qq[(size_t)ch * rows + r0 + t] = s;
            else          kk[(size_t)ch * rows + r0 + t] = s;
        }
    }
}

// ---------------------------------------------------------------------------
// Kernel 2: partial attention, QT=32 / KCH=128 / NCH=8.
// grid = 64 qtiles x 8 chunks = 512 blocks x 256 thr x 4 waves -- the exact
// geometry of the proven 14.7us kernel, but each block serves 32 q-rows, so
// K/V L2/L3 traffic halves (131MB -> 65MB; the dominant attn cost).
// kf/pf fragments are SHARED across the 2 q-subtiles -> same loads, same
// MFMA count per wave (2kbi x [8 kf-loads + 2qs x 8 MFMA]; PV 4ki x 2qs x 4).
// P_s[32][128] bf16, XOR swizzle (row&7 = lr&7 on both write and read).
// ---------------------------------------------------------------------------
__global__ __launch_bounds__(256, 2) void attn_part_mfma(
    const unsigned short* __restrict__ Qb, const unsigned short* __restrict__ Kb,
    const unsigned short* __restrict__ VB,
    const float* __restrict__ qq, const float* __restrict__ kk,  // [2][rows]
    float* __restrict__ Opart, float* __restrict__ esum)
{
    __shared__ unsigned short P_s[QT * KCH];   // 8 KB
    __shared__ float kk_s[KCH];
    __shared__ float qq_s[QT];
    __shared__ float es_red[4][QT];

    const int t = threadIdx.x;
    const int w = t >> 6, l = t & 63, lr = l & 15, lc = l >> 4;
    const int qtile = blockIdx.x >> 3;         // 64 qtiles
    const int c = blockIdx.x & 7;              // 8 k-chunks
    const int rowbase = qtile * QT;            // global row
    const int b = rowbase >> 10;
    const int s0 = c * KCH;                    // chunk start within batch
    const size_t rows = (size_t)BB * SS;

    if (t < KCH) kk_s[t] = kk[b * SS + s0 + t] + kk[rows + b * SS + s0 + t];
    if (t < QT)  qq_s[t] = qq[rowbase + t] + qq[rows + rowbase + t];

    // Q A-frags for both 16-row subtiles
    bf16x8 qf[2][8];
#pragma unroll
    for (int qs = 0; qs < 2; ++qs)
#pragma unroll
        for (int db = 0; db < 8; ++db)
            qf[qs][db] = *(const bf16x8*)(
                Qb + (size_t)(rowbase + 16 * qs + lr) * DD + db * 32 + 8 * lc);

    __syncthreads();

    // ---- QK^T + exp: wave w owns k-cols [32w, 32w+32) ----
    float psum[2][4];
#pragma unroll
    for (int qs = 0; qs < 2; ++qs)
#pragma unroll
        for (int r = 0; r < 4; ++r) psum[qs][r] = 0.f;

#pragma unroll
    for (int kbi = 0; kbi < 2; ++kbi) {
        const int kb = 32 * w + 16 * kbi;
        // load K-frags once, reuse for both q-subtiles
        bf16x8 kf[8];
#pragma unroll
        for (int db = 0; db < 8; ++db)
            kf[db] = *(const bf16x8*)(
                Kb + (size_t)(b * SS + s0 + kb + lr) * DD + db * 32 + 8 * lc);

        const int kcol = kb + lr;
        const float kkv = kk_s[kcol];
#pragma unroll
        for (int qs = 0; qs < 2; ++qs) {
            f32x4 acc = {0.f, 0.f, 0.f, 0.f};
#pragma unroll
            for (int db = 0; db < 8; ++db)
                acc = __builtin_amdgcn_mfma_f32_16x16x32_bf16(qf[qs][db], kf[db], acc, 0, 0, 0);
#pragma unroll
            for (int r = 0; r < 4; ++r) {
                const int qi = 16 * qs + lc * 4 + r;
                const float d2 = fmaxf(qq_s[qi] + kkv - 2.f * acc[r], 0.f);
                const float e = __expf(-sqrtf(d2) * 0.0625f);
                psum[qs][r] += e;
                P_s[qi * KCH + (kcol ^ ((qi & 7) << 3))] = f2bf(e);
            }
        }
    }
    // per-row e-sums: reduce across lr, then across waves via LDS
#pragma unroll
    for (int qs = 0; qs < 2; ++qs)
#pragma unroll
        for (int r = 0; r < 4; ++r) {
            float s = psum[qs][r];
#pragma unroll
            for (int m = 1; m < 16; m <<= 1) s += __shfl_xor(s, m, 64);
            if (lr == 0) es_red[w][16 * qs + lc * 4 + r] = s;
        }
    __syncthreads();   // publishes P_s + es_red
    if (t < QT)
        esum[(size_t)c * rows + rowbase + t] =
            es_red[0][t] + es_red[1][t] + es_red[2][t] + es_red[3][t];

    // ---- PV: wave w owns d-cols [64w, 64w+64) ----
    f32x4 acc2[2][4];
#pragma unroll
    for (int qs = 0; qs < 2; ++qs)
#pragma unroll
        for (int i = 0; i < 4; ++i) acc2[qs][i] = (f32x4){0.f, 0.f, 0.f, 0.f};

#pragma unroll
    for (int ki = 0; ki < KCH / 32; ++ki) {    // 4 iters
        // P-frags for both q-subtiles; V-frags shared across subtiles
        bf16x8 pf[2];
#pragma unroll
        for (int qs = 0; qs < 2; ++qs)
            pf[qs] = *(const bf16x8*)(
                P_s + (16 * qs + lr) * KCH + ((32 * ki + 8 * lc) ^ ((lr & 7) << 3)));
        const size_t tbase =
            ((size_t)((b * 32 + c * (KCH / 32) + ki) * 16 + 4 * w) << 9) + l * 8;
#pragma unroll
        for (int dbi = 0; dbi < 4; ++dbi) {
            bf16x8 vf = *(const bf16x8*)(VB + tbase + ((size_t)dbi << 9));
#pragma unroll
            for (int qs = 0; qs < 2; ++qs)
                acc2[qs][dbi] = __builtin_amdgcn_mfma_f32_16x16x32_bf16(
                    pf[qs], vf, acc2[qs][dbi], 0, 0, 0);
        }
    }
#pragma unroll
    for (int qs = 0; qs < 2; ++qs)
#pragma unroll
        for (int dbi = 0; dbi < 4; ++dbi)
#pragma unroll
            for (int r = 0; r < 4; ++r)
                Opart[((size_t)c * rows + rowbase + 16 * qs + lc * 4 + r) * DD
                      + 64 * w + 16 * dbi + lr] = acc2[qs][dbi][r];
}

// ---------------------------------------------------------------------------
// Kernel 3: chunk-sum + normalize -> bf16 att rows (R19 structure, NCH=8).
// Reads Opart once (16.8MB). 256 blocks x 256 thr.
// ---------------------------------------------------------------------------
__global__ __launch_bounds__(256) void reduce_att(
    const float* __restrict__ Opart, const float* __restrict__ esum,
    unsigned short* __restrict__ attb)
{
    const size_t rows = (size_t)BB * SS;
    const int u = blockIdx.x * 256 + threadIdx.x;   // 65536 units
    const int row = u >> 5;
    const int d8 = (u & 31) * 8;

    float den = 0.f;
#pragma unroll
    for (int c = 0; c < NCH; ++c) den += esum[(size_t)c * rows + row];
    const float inv = 1.f / den;

    float s0 = 0.f, s1 = 0.f, s2 = 0.f, s3 = 0.f;
    float s4 = 0.f, s5 = 0.f, s6 = 0.f, s7 = 0.f;
#pragma unroll
    for (int c = 0; c < NCH; ++c) {
        const float* p = Opart + ((size_t)c * rows + row) * DD + d8;
        float4 a0 = *(const float4*)(p);
        float4 a1 = *(const float4*)(p + 4);
        s0 += a0.x; s1 += a0.y; s2 += a0.z; s3 += a0.w;
        s4 += a1.x; s5 += a1.y; s6 += a1.z; s7 += a1.w;
    }
    bf16x8 a;
    a[0] = (short)f2bf(s0 * inv); a[1] = (short)f2bf(s1 * inv);
    a[2] = (short)f2bf(s2 * inv); a[3] = (short)f2bf(s3 * inv);
    a[4] = (short)f2bf(s4 * inv); a[5] = (short)f2bf(s5 * inv);
    a[6] = (short)f2bf(s6 * inv); a[7] = (short)f2bf(s7 * inv);
    *(bf16x8*)(attb + (size_t)row * DD + d8) = a;
}

// ---------------------------------------------------------------------------
// Kernel 4: output projection via MFMA with LDS staging (R19 verbatim).
// ---------------------------------------------------------------------------
__global__ __launch_bounds__(256, 2) void outproj_mfma(
    const unsigned short* __restrict__ attb,
    const unsigned short* __restrict__ Wob, const float* __restrict__ bo,
    float* __restrict__ out)
{
    __shared__ unsigned short att_s[16 * 264];   // 8.25 KB padded
    const int t = threadIdx.x;
    const int w = t >> 6, l = t & 63, lr = l & 15, lc = l >> 4;
    const int r0 = (blockIdx.x >> 2) * 16;   // global row
    const int ch = blockIdx.x & 3;           // col quarter

#pragma unroll
    for (int i = 0; i < 2; ++i) {
        const int u = t + i * 256;
        const int row = u >> 5;
        const int d8 = (u & 31) * 8;
        *(bf16x8*)(att_s + row * 264 + d8) =
            *(const bf16x8*)(attb + (size_t)(r0 + row) * DD + d8);
    }
    __syncthreads();

    bf16x8 af[8];
#pragma unroll
    for (int db = 0; db < 8; ++db)
        af[db] = *(const bf16x8*)(att_s + lr * 264 + db * 32 + 8 * lc);

    const int jb = 64 * ch + 16 * w;
    f32x4 acc = {0.f, 0.f, 0.f, 0.f};
#pragma unroll
    for (int db = 0; db < 8; ++db) {
        bf16x8 bf = *(const bf16x8*)(Wob + (size_t)(jb + lr) * DD + db * 32 + 8 * lc);
        acc = __builtin_amdgcn_mfma_f32_16x16x32_bf16(af[db], bf, acc, 0, 0, 0);
    }
    const float bov = bo[jb + lr];
#pragma unroll
    for (int r = 0; r < 4; ++r)
        out[(size_t)(r0 + lc * 4 + r) * DD + jb + lr] = acc[r] + bov;
}

// ---------------------------------------------------------------------------
extern "C" void kernel_launch(void* const* d_in, const int* in_sizes, int n_in,
                              void* d_out, int out_size, void* d_ws, size_t ws_size,
                              hipStream_t stream) {
    const float* x  = (const float*)d_in[0];
    const float* Wq = (const float*)d_in[1];
    const float* bq = (const float*)d_in[2];
    const float* Wk = (const float*)d_in[3];
    const float* bk = (const float*)d_in[4];
    const float* Wv = (const float*)d_in[5];
    const float* bv = (const float*)d_in[6];
    const float* Wo = (const float*)d_in[7];
    const float* bo = (const float*)d_in[8];
    float* out = (float*)d_out;

    // ws layout (bf16): Qb | Kb | VB | Wqb | Wkb | Wvb | Wob | attb ||
    //                   qq[2][rows] | kk[2][rows] | esum[8][rows] | Opart (fp32)
    const size_t rows = (size_t)BB * SS;            // 2048
    unsigned short* Qb   = (unsigned short*)d_ws;
    unsigned short* Kb   = Qb + rows * DD;
    unsigned short* VB   = Kb + rows * DD;
    unsigned short* Wqb  = VB + rows * DD;
    unsigned short* Wkb  = Wqb + (size_t)DD * DD;
    unsigned short* Wvb  = Wkb + (size_t)DD * DD;
    unsigned short* Wob  = Wvb + (size_t)DD * DD;
    unsigned short* attb = Wob + (size_t)DD * DD;
    float* qq    = (float*)(attb + rows * DD);       // 2*rows
    float* kk    = qq + 2 * rows;                    // 2*rows
    float* esum  = kk + 2 * rows;                    // NCH*rows
    float* Opart = esum + (size_t)NCH * rows;        // NCH*rows*DD floats

    cvt_w<<<128, 256, 0, stream>>>(Wq, Wk, Wv, Wo, Wqb, Wkb, Wvb, Wob);
    qkv_mfma<<<768, 256, 0, stream>>>(
        x, Wqb, bq, Wkb, bk, Wvb, bv, Qb, Kb, VB, qq, kk);
    attn_part_mfma<<<(int)(rows / QT) * NCH, 256, 0, stream>>>(
        Qb, Kb, VB, qq, kk, Opart, esum);
    reduce_att<<<256, 256, 0, stream>>>(Opart, esum, attb);
    outproj_mfma<<<(int)(rows / 16) * 4, 256, 0, stream>>>(
        attb, Wob, bo, out);
}

// Round 22
// 41.944 us; speedup vs baseline: 1.5979x; 1.1405x over previous
//
#include <hip/hip_runtime.h>
#include <hip/hip_bf16.h>

#define BB 2
#define SS 1024
#define DD 256
#define NCH 8           // k-chunks in attn
#define KCH 128         // k-chunk size
#define QT 32           // q-rows per attn block

typedef __attribute__((ext_vector_type(8))) short bf16x8;
typedef __attribute__((ext_vector_type(4))) float f32x4;

__device__ __forceinline__ unsigned short f2bf(float f) {
    __hip_bfloat16 h = __float2bfloat16(f);
    return *reinterpret_cast<unsigned short*>(&h);
}
__device__ __forceinline__ float bf2f(unsigned short u) {
    __hip_bfloat16 h;
    *reinterpret_cast<unsigned short*>(&h) = u;
    return __bfloat162float(h);
}
__device__ __forceinline__ bf16x8 cvt8(float4 f0, float4 f1) {
    bf16x8 o;
    o[0] = (short)f2bf(f0.x); o[1] = (short)f2bf(f0.y);
    o[2] = (short)f2bf(f0.z); o[3] = (short)f2bf(f0.w);
    o[4] = (short)f2bf(f1.x); o[5] = (short)f2bf(f1.y);
    o[6] = (short)f2bf(f1.z); o[7] = (short)f2bf(f1.w);
    return o;
}

// ---------------------------------------------------------------------------
// Kernel 0: fp32->bf16 conversion of the four weight matrices (R19 verbatim).
// ---------------------------------------------------------------------------
__global__ __launch_bounds__(256) void cvt_w(
    const float* __restrict__ Wq, const float* __restrict__ Wk,
    const float* __restrict__ Wv, const float* __restrict__ Wo,
    unsigned short* __restrict__ Wqb, unsigned short* __restrict__ Wkb,
    unsigned short* __restrict__ Wvb, unsigned short* __restrict__ Wob)
{
    const int u = blockIdx.x * 256 + threadIdx.x;   // unit = 8 elements
    const float* src;
    unsigned short* dst;
    int base;
    if (u < 8192)       { src = Wq; dst = Wqb; base = u; }
    else if (u < 16384) { src = Wk; dst = Wkb; base = u - 8192; }
    else if (u < 24576) { src = Wv; dst = Wvb; base = u - 16384; }
    else                { src = Wo; dst = Wob; base = u - 24576; }
    const float4* s4 = (const float4*)src + (size_t)base * 2;
    *(bf16x8*)(dst + (size_t)base * 8) = cvt8(s4[0], s4[1]);
}

// ---------------------------------------------------------------------------
// Kernel 1: Q,K,V projection via MFMA, column-split x2 + LDS-staged x.
// Block stages its 16-row x-tile ONCE (fp32->bf16 in LDS, 8.25KB padded);
// all 4 waves read A-frags from LDS instead of each re-loading 16KB fp32
// from L2 (48MB -> 12MB block-input traffic). Same cvt8 + MFMA order ->
// bit-identical results.
// ---------------------------------------------------------------------------
__global__ __launch_bounds__(256, 2) void qkv_mfma(
    const float* __restrict__ x,
    const unsigned short* __restrict__ Wqb, const float* __restrict__ bq,
    const unsigned short* __restrict__ Wkb, const float* __restrict__ bk,
    const unsigned short* __restrict__ Wvb, const float* __restrict__ bv,
    unsigned short* __restrict__ Qb, unsigned short* __restrict__ Kb,
    unsigned short* __restrict__ VB,
    float* __restrict__ qq, float* __restrict__ kk)   // [2][BB*SS] partials
{
    __shared__ unsigned short xs[16 * 264];   // 8.25 KB padded
    __shared__ float red[4][16];
    const int t = threadIdx.x;
    const int w = t >> 6, l = t & 63, lr = l & 15, lc = l >> 4;
    const int bx = blockIdx.x;
    const int mat = bx % 3;
    const int rest = bx / 3;
    const int tile = rest >> 1;
    const int ch = rest & 1;                 // column half
    const int r0 = tile * 16;
    const int b = r0 >> 10;
    const int s_in_base = r0 & (SS - 1);
    const size_t rows = (size_t)BB * SS;

    const unsigned short* W = (mat == 0) ? Wqb : (mat == 1) ? Wkb : Wvb;
    const float* bias       = (mat == 0) ? bq  : (mat == 1) ? bk  : bv;

    // cooperative stage + convert: 512 units of 8 elems; thread t does 2
#pragma unroll
    for (int i = 0; i < 2; ++i) {
        const int u = t + i * 256;
        const int row = u >> 5;
        const int d8 = (u & 31) * 8;
        const float* xp = x + (size_t)(r0 + row) * DD + d8;
        *(bf16x8*)(xs + row * 264 + d8) =
            cvt8(*(const float4*)(xp), *(const float4*)(xp + 4));
    }
    __syncthreads();

    // A-frags from LDS (same bf16 values as before)
    bf16x8 af[8];
#pragma unroll
    for (int db = 0; db < 8; ++db)
        af[db] = *(const bf16x8*)(xs + lr * 264 + db * 32 + 8 * lc);

    float nrm[4] = {0.f, 0.f, 0.f, 0.f};

#pragma unroll
    for (int cb = 0; cb < 2; ++cb) {
        const int jb = 128 * ch + 32 * w + 16 * cb;
        f32x4 acc = {0.f, 0.f, 0.f, 0.f};
#pragma unroll
        for (int db = 0; db < 8; ++db) {
            bf16x8 bf = *(const bf16x8*)(W + (size_t)(jb + lr) * DD + db * 32 + 8 * lc);
            acc = __builtin_amdgcn_mfma_f32_16x16x32_bf16(af[db], bf, acc, 0, 0, 0);
        }
        const float bv_ = bias[jb + lr];
#pragma unroll
        for (int r = 0; r < 4; ++r) {
            const int srow = r0 + lc * 4 + r;     // C/D: row=(l>>4)*4+r, col=l%16
            const float v = acc[r] + bv_;
            const unsigned short h = f2bf(v);
            if (mat == 0) {
                Qb[(size_t)srow * DD + jb + lr] = h;
                const float hv = bf2f(h); nrm[r] += hv * hv;
            } else if (mat == 1) {
                Kb[(size_t)srow * DD + jb + lr] = h;
                const float hv = bf2f(h); nrm[r] += hv * hv;
            } else {
                // VB layout: tile(b, kb32=s/32, db16=d/16) of 1024B
                const int s_in = s_in_base + lc * 4 + r;
                const int kb32 = s_in >> 5;
                const int kslot = (s_in >> 3) & 3;
                const int jj = s_in & 7;
                const int db16 = ch * 8 + 2 * w + cb;
                const size_t off = ((size_t)((b * 32 + kb32) * 16 + db16) << 9)
                                 + ((kslot * 16 + lr) << 3) + jj;
                VB[off] = h;
            }
        }
    }

    if (mat < 2) {
#pragma unroll
        for (int r = 0; r < 4; ++r) {
            float n = nrm[r];
#pragma unroll
            for (int m = 1; m < 16; m <<= 1) n += __shfl_xor(n, m, 64);
            if (lr == 0) red[w][lc * 4 + r] = n;
        }
        __syncthreads();
        if (t < 16) {
            const float s = red[0][t] + red[1][t] + red[2][t] + red[3][t];
            if (mat == 0) qq[(size_t)ch * rows + r0 + t] = s;
            else          kk[(size_t)ch * rows + r0 + t] = s;
        }
    }
}

// ---------------------------------------------------------------------------
// Kernel 2: partial attention QT=32/KCH=128/NCH=8 (R21) + LDS-staged Q.
// Block stages its 32-row Q-tile ONCE (16.5KB); all 4 waves read qf frags
// from LDS (32MB -> 8MB Q traffic). kf/V unchanged (per-wave distinct).
// ---------------------------------------------------------------------------
__global__ __launch_bounds__(256, 2) void attn_part_mfma(
    const unsigned short* __restrict__ Qb, const unsigned short* __restrict__ Kb,
    const unsigned short* __restrict__ VB,
    const float* __restrict__ qq, const float* __restrict__ kk,  // [2][rows]
    float* __restrict__ Opart, float* __restrict__ esum)
{
    __shared__ unsigned short Q_s[QT * 264];   // 16.5 KB padded
    __shared__ unsigned short P_s[QT * KCH];   // 8 KB
    __shared__ float kk_s[KCH];
    __shared__ float qq_s[QT];
    __shared__ float es_red[4][QT];

    const int t = threadIdx.x;
    const int w = t >> 6, l = t & 63, lr = l & 15, lc = l >> 4;
    const int qtile = blockIdx.x >> 3;         // 64 qtiles
    const int c = blockIdx.x & 7;              // 8 k-chunks
    const int rowbase = qtile * QT;            // global row
    const int b = rowbase >> 10;
    const int s0 = c * KCH;                    // chunk start within batch
    const size_t rows = (size_t)BB * SS;

    if (t < KCH) kk_s[t] = kk[b * SS + s0 + t] + kk[rows + b * SS + s0 + t];
    if (t < QT)  qq_s[t] = qq[rowbase + t] + qq[rows + rowbase + t];

    // cooperative stage Q: 1024 units of 8 bf16; thread t does 4
#pragma unroll
    for (int i = 0; i < 4; ++i) {
        const int u = t + i * 256;
        const int row = u >> 5;
        const int d8 = (u & 31) * 8;
        *(bf16x8*)(Q_s + row * 264 + d8) =
            *(const bf16x8*)(Qb + (size_t)(rowbase + row) * DD + d8);
    }
    __syncthreads();

    // Q A-frags from LDS for both 16-row subtiles
    bf16x8 qf[2][8];
#pragma unroll
    for (int qs = 0; qs < 2; ++qs)
#pragma unroll
        for (int db = 0; db < 8; ++db)
            qf[qs][db] = *(const bf16x8*)(
                Q_s + (16 * qs + lr) * 264 + db * 32 + 8 * lc);

    // ---- QK^T + exp: wave w owns k-cols [32w, 32w+32) ----
    float psum[2][4];
#pragma unroll
    for (int qs = 0; qs < 2; ++qs)
#pragma unroll
        for (int r = 0; r < 4; ++r) psum[qs][r] = 0.f;

#pragma unroll
    for (int kbi = 0; kbi < 2; ++kbi) {
        const int kb = 32 * w + 16 * kbi;
        bf16x8 kf[8];
#pragma unroll
        for (int db = 0; db < 8; ++db)
            kf[db] = *(const bf16x8*)(
                Kb + (size_t)(b * SS + s0 + kb + lr) * DD + db * 32 + 8 * lc);

        const int kcol = kb + lr;
        const float kkv = kk_s[kcol];
#pragma unroll
        for (int qs = 0; qs < 2; ++qs) {
            f32x4 acc = {0.f, 0.f, 0.f, 0.f};
#pragma unroll
            for (int db = 0; db < 8; ++db)
                acc = __builtin_amdgcn_mfma_f32_16x16x32_bf16(qf[qs][db], kf[db], acc, 0, 0, 0);
#pragma unroll
            for (int r = 0; r < 4; ++r) {
                const int qi = 16 * qs + lc * 4 + r;
                const float d2 = fmaxf(qq_s[qi] + kkv - 2.f * acc[r], 0.f);
                const float e = __expf(-sqrtf(d2) * 0.0625f);
                psum[qs][r] += e;
                P_s[qi * KCH + (kcol ^ ((qi & 7) << 3))] = f2bf(e);
            }
        }
    }
    // per-row e-sums
#pragma unroll
    for (int qs = 0; qs < 2; ++qs)
#pragma unroll
        for (int r = 0; r < 4; ++r) {
            float s = psum[qs][r];
#pragma unroll
            for (int m = 1; m < 16; m <<= 1) s += __shfl_xor(s, m, 64);
            if (lr == 0) es_red[w][16 * qs + lc * 4 + r] = s;
        }
    __syncthreads();   // publishes P_s + es_red
    if (t < QT)
        esum[(size_t)c * rows + rowbase + t] =
            es_red[0][t] + es_red[1][t] + es_red[2][t] + es_red[3][t];

    // ---- PV: wave w owns d-cols [64w, 64w+64) ----
    f32x4 acc2[2][4];
#pragma unroll
    for (int qs = 0; qs < 2; ++qs)
#pragma unroll
        for (int i = 0; i < 4; ++i) acc2[qs][i] = (f32x4){0.f, 0.f, 0.f, 0.f};

#pragma unroll
    for (int ki = 0; ki < KCH / 32; ++ki) {    // 4 iters
        bf16x8 pf[2];
#pragma unroll
        for (int qs = 0; qs < 2; ++qs)
            pf[qs] = *(const bf16x8*)(
                P_s + (16 * qs + lr) * KCH + ((32 * ki + 8 * lc) ^ ((lr & 7) << 3)));
        const size_t tbase =
            ((size_t)((b * 32 + c * (KCH / 32) + ki) * 16 + 4 * w) << 9) + l * 8;
#pragma unroll
        for (int dbi = 0; dbi < 4; ++dbi) {
            bf16x8 vf = *(const bf16x8*)(VB + tbase + ((size_t)dbi << 9));
#pragma unroll
            for (int qs = 0; qs < 2; ++qs)
                acc2[qs][dbi] = __builtin_amdgcn_mfma_f32_16x16x32_bf16(
                    pf[qs], vf, acc2[qs][dbi], 0, 0, 0);
        }
    }
#pragma unroll
    for (int qs = 0; qs < 2; ++qs)
#pragma unroll
        for (int dbi = 0; dbi < 4; ++dbi)
#pragma unroll
            for (int r = 0; r < 4; ++r)
                Opart[((size_t)c * rows + rowbase + 16 * qs + lc * 4 + r) * DD
                      + 64 * w + 16 * dbi + lr] = acc2[qs][dbi][r];
}

// ---------------------------------------------------------------------------
// Kernel 3: chunk-sum + normalize -> bf16 att rows (R21 verbatim, NCH=8).
// ---------------------------------------------------------------------------
__global__ __launch_bounds__(256) void reduce_att(
    const float* __restrict__ Opart, const float* __restrict__ esum,
    unsigned short* __restrict__ attb)
{
    const size_t rows = (size_t)BB * SS;
    const int u = blockIdx.x * 256 + threadIdx.x;   // 65536 units
    const int row = u >> 5;
    const int d8 = (u & 31) * 8;

    float den = 0.f;
#pragma unroll
    for (int c = 0; c < NCH; ++c) den += esum[(size_t)c * rows + row];
    const float inv = 1.f / den;

    float s0 = 0.f, s1 = 0.f, s2 = 0.f, s3 = 0.f;
    float s4 = 0.f, s5 = 0.f, s6 = 0.f, s7 = 0.f;
#pragma unroll
    for (int c = 0; c < NCH; ++c) {
        const float* p = Opart + ((size_t)c * rows + row) * DD + d8;
        float4 a0 = *(const float4*)(p);
        float4 a1 = *(const float4*)(p + 4);
        s0 += a0.x; s1 += a0.y; s2 += a0.z; s3 += a0.w;
        s4 += a1.x; s5 += a1.y; s6 += a1.z; s7 += a1.w;
    }
    bf16x8 a;
    a[0] = (short)f2bf(s0 * inv); a[1] = (short)f2bf(s1 * inv);
    a[2] = (short)f2bf(s2 * inv); a[3] = (short)f2bf(s3 * inv);
    a[4] = (short)f2bf(s4 * inv); a[5] = (short)f2bf(s5 * inv);
    a[6] = (short)f2bf(s6 * inv); a[7] = (short)f2bf(s7 * inv);
    *(bf16x8*)(attb + (size_t)row * DD + d8) = a;
}

// ---------------------------------------------------------------------------
// Kernel 4: output projection via MFMA with LDS staging (R19 verbatim).
// ---------------------------------------------------------------------------
__global__ __launch_bounds__(256, 2) void outproj_mfma(
    const unsigned short* __restrict__ attb,
    const unsigned short* __restrict__ Wob, const float* __restrict__ bo,
    float* __restrict__ out)
{
    __shared__ unsigned short att_s[16 * 264];   // 8.25 KB padded
    const int t = threadIdx.x;
    const int w = t >> 6, l = t & 63, lr = l & 15, lc = l >> 4;
    const int r0 = (blockIdx.x >> 2) * 16;   // global row
    const int ch = blockIdx.x & 3;           // col quarter

#pragma unroll
    for (int i = 0; i < 2; ++i) {
        const int u = t + i * 256;
        const int row = u >> 5;
        const int d8 = (u & 31) * 8;
        *(bf16x8*)(att_s + row * 264 + d8) =
            *(const bf16x8*)(attb + (size_t)(r0 + row) * DD + d8);
    }
    __syncthreads();

    bf16x8 af[8];
#pragma unroll
    for (int db = 0; db < 8; ++db)
        af[db] = *(const bf16x8*)(att_s + lr * 264 + db * 32 + 8 * lc);

    const int jb = 64 * ch + 16 * w;
    f32x4 acc = {0.f, 0.f, 0.f, 0.f};
#pragma unroll
    for (int db = 0; db < 8; ++db) {
        bf16x8 bf = *(const bf16x8*)(Wob + (size_t)(jb + lr) * DD + db * 32 + 8 * lc);
        acc = __builtin_amdgcn_mfma_f32_16x16x32_bf16(af[db], bf, acc, 0, 0, 0);
    }
    const float bov = bo[jb + lr];
#pragma unroll
    for (int r = 0; r < 4; ++r)
        out[(size_t)(r0 + lc * 4 + r) * DD + jb + lr] = acc[r] + bov;
}

// ---------------------------------------------------------------------------
extern "C" void kernel_launch(void* const* d_in, const int* in_sizes, int n_in,
                              void* d_out, int out_size, void* d_ws, size_t ws_size,
                              hipStream_t stream) {
    const float* x  = (const float*)d_in[0];
    const float* Wq = (const float*)d_in[1];
    const float* bq = (const float*)d_in[2];
    const float* Wk = (const float*)d_in[3];
    const float* bk = (const float*)d_in[4];
    const float* Wv = (const float*)d_in[5];
    const float* bv = (const float*)d_in[6];
    const float* Wo = (const float*)d_in[7];
    const float* bo = (const float*)d_in[8];
    float* out = (float*)d_out;

    // ws layout (bf16): Qb | Kb | VB | Wqb | Wkb | Wvb | Wob | attb ||
    //                   qq[2][rows] | kk[2][rows] | esum[8][rows] | Opart (fp32)
    const size_t rows = (size_t)BB * SS;            // 2048
    unsigned short* Qb   = (unsigned short*)d_ws;
    unsigned short* Kb   = Qb + rows * DD;
    unsigned short* VB   = Kb + rows * DD;
    unsigned short* Wqb  = VB + rows * DD;
    unsigned short* Wkb  = Wqb + (size_t)DD * DD;
    unsigned short* Wvb  = Wkb + (size_t)DD * DD;
    unsigned short* Wob  = Wvb + (size_t)DD * DD;
    unsigned short* attb = Wob + (size_t)DD * DD;
    float* qq    = (float*)(attb + rows * DD);       // 2*rows
    float* kk    = qq + 2 * rows;                    // 2*rows
    float* esum  = kk + 2 * rows;                    // NCH*rows
    float* Opart = esum + (size_t)NCH * rows;        // NCH*rows*DD floats

    cvt_w<<<128, 256, 0, stream>>>(Wq, Wk, Wv, Wo, Wqb, Wkb, Wvb, Wob);
    qkv_mfma<<<768, 256, 0, stream>>>(
        x, Wqb, bq, Wkb, bk, Wvb, bv, Qb, Kb, VB, qq, kk);
    attn_part_mfma<<<(int)(rows / QT) * NCH, 256, 0, stream>>>(
        Qb, Kb, VB, qq, kk, Opart, esum);
    reduce_att<<<256, 256, 0, stream>>>(Opart, esum, attb);
    outproj_mfma<<<(int)(rows / 16) * 4, 256, 0, stream>>>(
        attb, Wob, bo, out);
}